// Round 2
// baseline (29.337 us; speedup 1.0000x reference)
//
#include <hip/hip_runtime.h>

#define NBINS 256
#define NCH 3
#define BLOCK 512
#define NWAVES 8              // 512 threads / 64 lanes
#define ELEMS_PER_THREAD 12   // 3 x float4; 12 % 3 == 0 so channel is compile-time

__global__ __launch_bounds__(BLOCK, 8) void hist_kernel(const float* __restrict__ in,
                                                        float* __restrict__ out,
                                                        int blocksPerBatch,
                                                        int floatsPerBatch,
                                                        float inv_n) {
    __shared__ unsigned int h[NWAVES][NCH * NBINS];   // 24 KB

    const int tid = threadIdx.x;
    // zero LDS histograms
    for (int i = tid; i < NWAVES * NCH * NBINS; i += BLOCK) {
        ((unsigned int*)h)[i] = 0u;
    }
    __syncthreads();

    const int b     = blockIdx.x / blocksPerBatch;
    const int chunk = blockIdx.x % blocksPerBatch;
    const int chunkFloats = floatsPerBatch / blocksPerBatch;      // 24576
    const float* base = in + (size_t)b * floatsPerBatch + (size_t)chunk * chunkFloats;
    const int w = tid >> 6;

    const int floatsPerIter = BLOCK * ELEMS_PER_THREAD;           // 6144
    const int iters = chunkFloats / floatsPerIter;                // 4

    for (int it = 0; it < iters; ++it) {
        const float4* p = (const float4*)(base + (size_t)it * floatsPerIter
                                               + (size_t)tid * ELEMS_PER_THREAD);
        float4 v0 = p[0];
        float4 v1 = p[1];
        float4 v2 = p[2];
        float v[ELEMS_PER_THREAD] = {v0.x, v0.y, v0.z, v0.w,
                                     v1.x, v1.y, v1.z, v1.w,
                                     v2.x, v2.y, v2.z, v2.w};
#pragma unroll
        for (int j = 0; j < ELEMS_PER_THREAD; ++j) {
            int bin = (int)floorf(v[j] * 256.0f);
            bin = bin < 0 ? 0 : (bin > NBINS - 1 ? NBINS - 1 : bin);
            const int c = j % NCH;   // compile-time constant under unroll
            atomicAdd(&h[w][c * NBINS + bin], 1u);
        }
    }
    __syncthreads();

    // reduce the 8 wave-private copies, scale exactly by 2^-18, and
    // accumulate directly into the transposed output out[b][bin][c].
    // Every addend is a multiple of 2^-18 and every partial sum is <= 1.0,
    // so float atomicAdd is exact and order-independent.
    float* dst = out + (size_t)b * (NCH * NBINS);
    for (int i = tid; i < NCH * NBINS; i += BLOCK) {
        unsigned int s = 0;
#pragma unroll
        for (int wv = 0; wv < NWAVES; ++wv) s += h[wv][i];
        if (s) {
            const int c   = i >> 8;          // i = c*256 + bin
            const int bin = i & (NBINS - 1);
            atomicAdd(&dst[bin * NCH + c], (float)s * inv_n);
        }
    }
}

extern "C" void kernel_launch(void* const* d_in, const int* in_sizes, int n_in,
                              void* d_out, int out_size, void* d_ws, size_t ws_size,
                              hipStream_t stream) {
    const float* in = (const float*)d_in[0];
    float* out = (float*)d_out;

    const int floatsPerBatch = 512 * 512 * 3;        // H*W*C
    const int total = in_sizes[0];
    const int B = total / floatsPerBatch;            // 32
    const float inv_n = 1.0f / (float)(512 * 512);   // 2^-18, exact

    hipMemsetAsync(d_out, 0, (size_t)out_size * sizeof(float), stream);

    const int blocksPerBatch = 32;                   // 1024 blocks x 512 thr, 4 iters
    hist_kernel<<<B * blocksPerBatch, BLOCK, 0, stream>>>(in, out, blocksPerBatch,
                                                          floatsPerBatch, inv_n);
}